// Round 3
// baseline (245.664 us; speedup 1.0000x reference)
//
#include <hip/hip_runtime.h>

// Problem constants (from reference setup_inputs)
constexpr int B  = 32;
constexpr int C  = 3;
constexpr int H  = 512;
constexpr int W  = 512;
constexpr int HP = H / 4;    // 128
constexpr int WP = W / 4;    // 128
constexpr int NP = B * HP * WP;   // 524288 = 2^19 pooled pixels
constexpr int PLANES = 6;         // (src in {x,pred}) x (c in 0..2)

// ---------------- Fast path (needs 14 MB workspace) ----------------
// Phase 1: maximal-streaming partial pool. One thread = one (src, c, pooled px).
// Each thread reads 4 float4 (4 rows x 4 cols of one channel of one array);
// consecutive lanes read consecutive float4 -> each instruction is a perfect
// 1 KB wave-contiguous burst from a single linear stream. 12288 blocks = 6x
// resident-wave capacity -> continuous wave replacement (m13 copy structure).
__global__ __launch_bounds__(256) void stream_pool_kernel(
        const float* __restrict__ x,
        const float* __restrict__ pred,
        float* __restrict__ q) {
    int idx   = blockIdx.x * 256 + threadIdx.x;   // 0 .. 6*NP-1
    int i     = idx & (NP - 1);
    int plane = idx >> 19;                        // 0..5, uniform per block
    const float* src = (plane < 3) ? x : pred;
    int c = (plane < 3) ? plane : plane - 3;

    int px = i & (WP - 1);
    int py = (i >> 7) & (HP - 1);
    int b  = i >> 14;
    size_t base = (((size_t)b * C + c) * H + (size_t)py * 4) * W + (size_t)px * 4;
    const float4* sp = (const float4*)(src + base);

    float4 r0 = sp[0 * (W / 4)];
    float4 r1 = sp[1 * (W / 4)];
    float4 r2 = sp[2 * (W / 4)];
    float4 r3 = sp[3 * (W / 4)];
    float s = (r0.x + r0.y + r0.z + r0.w) + (r1.x + r1.y + r1.z + r1.w)
            + (r2.x + r2.y + r2.z + r2.w) + (r3.x + r3.y + r3.z + r3.w);
    q[idx] = s;
}

// Phase 2a: combine the 6 plane partial sums into p (all L2-resident, 12 MB in).
__global__ __launch_bounds__(256) void combine_kernel(
        const float* __restrict__ q,
        float* __restrict__ p) {
    int i = blockIdx.x * 256 + threadIdx.x;
    float s = q[i] + q[i + NP] + q[i + 2 * NP]
            - q[i + 3 * NP] - q[i + 4 * NP] - q[i + 5 * NP];
    p[i] = s * (1.0f / 48.0f);
}

// ---------------- Fallback phase 1 (2 MB workspace) ----------------
__global__ __launch_bounds__(256) void pool_diff_kernel(
        const float* __restrict__ x,
        const float* __restrict__ pred,
        float* __restrict__ p) {
    int idx = blockIdx.x * blockDim.x + threadIdx.x;
    int px = idx & (WP - 1);
    int py = (idx >> 7) & (HP - 1);
    int b  = idx >> 14;
    size_t base = (((size_t)b * C) * H + (size_t)py * 4) * W + (size_t)px * 4;
    float s = 0.0f;
    #pragma unroll
    for (int c = 0; c < C; ++c) {
        const float4* xb = (const float4*)(x    + base + (size_t)c * H * W);
        const float4* pb = (const float4*)(pred + base + (size_t)c * H * W);
        #pragma unroll
        for (int r = 0; r < 4; ++r) {
            float4 xv = xb[r * (W / 4)];
            float4 pv = pb[r * (W / 4)];
            s += (xv.x - pv.x) + (xv.y - pv.y) + (xv.z - pv.z) + (xv.w - pv.w);
        }
    }
    p[idx] = s * (1.0f / 48.0f);
}

// Phase 2b: four neighbor diffs (zero pad), sum of squares, wave reduce,
// one pre-scaled atomicAdd per block.
__global__ __launch_bounds__(256) void grad_loss_kernel(
        const float* __restrict__ p,
        float* __restrict__ out) {
    int idx = blockIdx.x * blockDim.x + threadIdx.x;
    int px = idx & (WP - 1);
    int py = (idx >> 7) & (HP - 1);
    float c = p[idx];
    float l = (px > 0)      ? p[idx - 1]  : 0.0f;
    float r = (px < WP - 1) ? p[idx + 1]  : 0.0f;
    float u = (py > 0)      ? p[idx - WP] : 0.0f;
    float d = (py < HP - 1) ? p[idx + WP] : 0.0f;
    float g0 = c - l, g1 = c - r, g2 = c - u, g3 = c - d;
    float acc = g0 * g0 + g1 * g1 + g2 * g2 + g3 * g3;

    #pragma unroll
    for (int off = 32; off > 0; off >>= 1)
        acc += __shfl_down(acc, off, 64);

    __shared__ float ws_red[4];
    int lane = threadIdx.x & 63;
    int wid  = threadIdx.x >> 6;
    if (lane == 0) ws_red[wid] = acc;
    __syncthreads();
    if (threadIdx.x == 0) {
        float s = ws_red[0] + ws_red[1] + ws_red[2] + ws_red[3];
        atomicAdd(out, s * (1.0f / (float)NP));
    }
}

extern "C" void kernel_launch(void* const* d_in, const int* in_sizes, int n_in,
                              void* d_out, int out_size, void* d_ws, size_t ws_size,
                              hipStream_t stream) {
    const float* x    = (const float*)d_in[0];
    const float* pred = (const float*)d_in[1];
    float* out = (float*)d_out;

    hipMemsetAsync(out, 0, sizeof(float), stream);

    const size_t need = (size_t)(PLANES + 1) * NP * sizeof(float);  // 14 MB
    if (ws_size >= need) {
        float* q = (float*)d_ws;            // 6*NP floats (12 MB)
        float* p = q + (size_t)PLANES * NP; // NP floats (2 MB)
        stream_pool_kernel<<<PLANES * NP / 256, 256, 0, stream>>>(x, pred, q);
        combine_kernel<<<NP / 256, 256, 0, stream>>>(q, p);
        grad_loss_kernel<<<NP / 256, 256, 0, stream>>>(p, out);
    } else {
        float* p = (float*)d_ws;            // NP floats (2 MB)
        pool_diff_kernel<<<NP / 256, 256, 0, stream>>>(x, pred, p);
        grad_loss_kernel<<<NP / 256, 256, 0, stream>>>(p, out);
    }
}

// Round 4
// 220.672 us; speedup vs baseline: 1.1133x; 1.1133x over previous
//
#include <hip/hip_runtime.h>

// Problem constants (from reference setup_inputs)
constexpr int B  = 32;
constexpr int C  = 3;
constexpr int H  = 512;
constexpr int W  = 512;
constexpr int HP = H / 4;    // 128 pooled rows
constexpr int WP = W / 4;    // 128 pooled cols
constexpr int NP = B * HP * WP;   // 524288 pooled pixels

constexpr int TS = 32;            // interior tile (pooled px)
constexpr int HS = TS + 2;        // 34: tile + 1-px halo
constexpr int TILES_PER_IMG = (HP / TS) * (WP / TS);  // 4*4 = 16
constexpr int NBLOCKS = B * TILES_PER_IMG;            // 512

// One kernel does everything:
//   Phase A: compute pooled channel-mean difference p for a 34x34 halo tile
//            directly from raw x/pred (24 float4 loads per pooled pixel),
//            store into LDS.
//   Phase B: 4-direction neighbor diffs (zero-pad at image borders comes free:
//            halo cells outside the image hold 0), sum of squares over the
//            32x32 interior, wave+LDS reduce, one pre-scaled atomicAdd.
// Rationale: rounds 1-3 showed phase-1 is stuck at ~75us for ANY access
// structure (external wall); so we minimize kernel count + auxiliary traffic
// instead. No workspace use at all.
__global__ __launch_bounds__(256) void spatial_loss_fused(
        const float* __restrict__ x,
        const float* __restrict__ pred,
        float* __restrict__ out) {
    __shared__ float pt[HS][HS + 1];   // +1 pad: 34x35 floats = 4.8 KB

    int blk = blockIdx.x;
    int b   = blk >> 4;          // image index
    int ty  = (blk >> 2) & 3;    // tile row
    int tx  = blk & 3;           // tile col
    int tid = threadIdx.x;

    // ---- Phase A: fill 34x34 pooled halo tile ----
    for (int i = tid; i < HS * HS; i += 256) {
        int hy = i / HS;
        int hx = i - hy * HS;
        int gy = ty * TS + hy - 1;   // pooled coords, -1..128
        int gx = tx * TS + hx - 1;
        float s = 0.0f;
        if ((unsigned)gy < (unsigned)HP && (unsigned)gx < (unsigned)WP) {
            size_t base = (((size_t)b * C) * H + (size_t)gy * 4) * W + (size_t)gx * 4;
            #pragma unroll
            for (int c = 0; c < C; ++c) {
                const float4* xb = (const float4*)(x    + base + (size_t)c * H * W);
                const float4* pb = (const float4*)(pred + base + (size_t)c * H * W);
                #pragma unroll
                for (int r = 0; r < 4; ++r) {
                    float4 xv = xb[r * (W / 4)];
                    float4 pv = pb[r * (W / 4)];
                    s += (xv.x - pv.x) + (xv.y - pv.y) + (xv.z - pv.z) + (xv.w - pv.w);
                }
            }
            s *= (1.0f / 48.0f);
        }
        pt[hy][hx] = s;
    }
    __syncthreads();

    // ---- Phase B: gradient sum-of-squares over 32x32 interior ----
    float acc = 0.0f;
    #pragma unroll
    for (int j = 0; j < (TS * TS) / 256; ++j) {
        int i  = tid + j * 256;
        int iy = i >> 5;         // 0..31
        int ix = i & 31;
        float c = pt[iy + 1][ix + 1];
        float l = pt[iy + 1][ix + 0];
        float r = pt[iy + 1][ix + 2];
        float u = pt[iy + 0][ix + 1];
        float d = pt[iy + 2][ix + 1];
        float g0 = c - l, g1 = c - r, g2 = c - u, g3 = c - d;
        acc += g0 * g0 + g1 * g1 + g2 * g2 + g3 * g3;
    }

    // wave64 shuffle reduce
    #pragma unroll
    for (int off = 32; off > 0; off >>= 1)
        acc += __shfl_down(acc, off, 64);

    __shared__ float ws_red[4];
    int lane = tid & 63;
    int wid  = tid >> 6;
    if (lane == 0) ws_red[wid] = acc;
    __syncthreads();
    if (tid == 0) {
        float s = ws_red[0] + ws_red[1] + ws_red[2] + ws_red[3];
        atomicAdd(out, s * (1.0f / (float)NP));
    }
}

extern "C" void kernel_launch(void* const* d_in, const int* in_sizes, int n_in,
                              void* d_out, int out_size, void* d_ws, size_t ws_size,
                              hipStream_t stream) {
    const float* x    = (const float*)d_in[0];
    const float* pred = (const float*)d_in[1];
    float* out = (float*)d_out;

    // out is poisoned 0xAA before every launch — zero it (capture-safe).
    hipMemsetAsync(out, 0, sizeof(float), stream);

    spatial_loss_fused<<<NBLOCKS, 256, 0, stream>>>(x, pred, out);
}

// Round 5
// 219.550 us; speedup vs baseline: 1.1189x; 1.0051x over previous
//
#include <hip/hip_runtime.h>

// Problem constants (from reference setup_inputs)
constexpr int B  = 32;
constexpr int C  = 3;
constexpr int H  = 512;
constexpr int W  = 512;
constexpr int HP = H / 4;    // 128 pooled rows
constexpr int WP = W / 4;    // 128 pooled cols
constexpr int NP = B * HP * WP;   // 524288 pooled pixels

// Tile: 64 (x) x 32 (y) owned pooled pixels, halo 1 row ABOVE + 1 col LEFT.
// Pair-counting: E*NP = 2*sum(adjacent-pair diffs^2) + sum(border p^2);
// each block counts pairs (up-neighbor, left-neighbor) for its OWNED pixels
// only -> halo needed only on top/left. Zero-filled halo at image borders
// makes the border term (c-0)^2 = c^2 with weight 1 automatically.
// Overhead vs raw inputs: +3.1% logical bytes (vs +12.9% for the round-4
// 2-sided halo). 256 blocks = 1/CU.
constexpr int TX = 64;            // owned cols per tile
constexpr int TY = 32;            // owned rows per tile
constexpr int HX = TX + 1;        // 65 (left halo)
constexpr int HY = TY + 1;        // 33 (top halo)
constexpr int TILES_X = WP / TX;  // 2
constexpr int TILES_Y = HP / TY;  // 4
constexpr int NBLOCKS = B * TILES_X * TILES_Y;  // 256

__global__ __launch_bounds__(256) void spatial_loss_fused(
        const float* __restrict__ x,
        const float* __restrict__ pred,
        float* __restrict__ out) {
    __shared__ float pt[HY][HX];   // 33x65 floats = 8.6 KB; flat addr == i

    int blk = blockIdx.x;
    int b   = blk >> 3;           // image
    int ty  = (blk >> 1) & 3;     // tile row
    int tx  = blk & 1;            // tile col
    int y0  = ty * TY;
    int x0  = tx * TX;
    int tid = threadIdx.x;

    // ---- Phase A: pooled channel-mean diff for the 33x65 halo tile ----
    for (int i = tid; i < HY * HX; i += 256) {
        int hy = i / HX;
        int hx = i - hy * HX;
        int gy = y0 + hy - 1;     // pooled coords, -1..127
        int gx = x0 + hx - 1;
        float s = 0.0f;
        if ((unsigned)gy < (unsigned)HP && (unsigned)gx < (unsigned)WP) {
            size_t base = (((size_t)b * C) * H + (size_t)gy * 4) * W + (size_t)gx * 4;
            #pragma unroll
            for (int c = 0; c < C; ++c) {
                const float4* xb = (const float4*)(x    + base + (size_t)c * H * W);
                const float4* pb = (const float4*)(pred + base + (size_t)c * H * W);
                #pragma unroll
                for (int r = 0; r < 4; ++r) {
                    float4 xv = xb[r * (W / 4)];
                    float4 pv = pb[r * (W / 4)];
                    s += (xv.x - pv.x) + (xv.y - pv.y) + (xv.z - pv.z) + (xv.w - pv.w);
                }
            }
            s *= (1.0f / 48.0f);
        }
        pt[hy][hx] = s;   // addr = i -> consecutive lanes, conflict-free
    }
    __syncthreads();

    // ---- Phase B: pair-counted gradient sum over owned 32x64 pixels ----
    float acc = 0.0f;
    #pragma unroll
    for (int j = 0; j < (TY * TX) / 256; ++j) {
        int i  = tid + j * 256;
        int r  = i >> 6;          // 0..31
        int xx = i & 63;          // 0..63
        int gy = y0 + r;
        int gx = x0 + xx;
        float c  = pt[r + 1][xx + 1];
        float up = pt[r + 0][xx + 1];   // zero if gy==0 (image border)
        float lf = pt[r + 1][xx + 0];   // zero if gx==0
        float dy = c - up;
        float dx = c - lf;
        float wy = (gy > 0) ? 2.0f : 1.0f;  // interior pair counted twice
        float wx = (gx > 0) ? 2.0f : 1.0f;
        acc += wy * dy * dy + wx * dx * dx;
        if (gy == HP - 1) acc += c * c;     // bottom border (d3)
        if (gx == WP - 1) acc += c * c;     // right border (d1)
    }

    // wave64 shuffle reduce -> LDS -> one pre-scaled atomicAdd per block
    #pragma unroll
    for (int off = 32; off > 0; off >>= 1)
        acc += __shfl_down(acc, off, 64);

    __shared__ float ws_red[4];
    int lane = tid & 63;
    int wid  = tid >> 6;
    if (lane == 0) ws_red[wid] = acc;
    __syncthreads();
    if (tid == 0) {
        float s = ws_red[0] + ws_red[1] + ws_red[2] + ws_red[3];
        atomicAdd(out, s * (1.0f / (float)NP));
    }
}

extern "C" void kernel_launch(void* const* d_in, const int* in_sizes, int n_in,
                              void* d_out, int out_size, void* d_ws, size_t ws_size,
                              hipStream_t stream) {
    const float* x    = (const float*)d_in[0];
    const float* pred = (const float*)d_in[1];
    float* out = (float*)d_out;

    // d_out is poisoned 0xAA before every launch — zero it (capture-safe).
    hipMemsetAsync(out, 0, sizeof(float), stream);

    spatial_loss_fused<<<NBLOCKS, 256, 0, stream>>>(x, pred, out);
}